// Round 6
// baseline (77.049 us; speedup 1.0000x reference)
//
#include <hip/hip_runtime.h>

#define EPS_F 1e-6f
#define LOG2E 1.4426950408889634f

typedef float f4a __attribute__((ext_vector_type(4), aligned(16)));

// Force a (known-uniform) float into an SGPR.
__device__ __forceinline__ float rfl(float x) {
    return __builtin_bit_cast(float, __builtin_amdgcn_readfirstlane(__builtin_bit_cast(int, x)));
}

// Kernel 1: partial sums.
// grid = 2048 = B(8) x m-tiles(16, 64 m) x n-chunks(16, 64 n) -> 8 blocks/CU,
// 32 waves/CU (max occupancy; LB(256,8) caps VGPR at 64). lane <-> m; wave wv
// sums rows [wv*16, wv*16+16) of the block's 64-n chunk. feat/xa staged in LDS
// (rows padded to 16/4 floats, all b128-aligned); inner-loop ds_reads are
// all-lanes-same-address broadcasts with immediate offsets. 4-wave partials
// combined in LDS (overlaid on staging after a barrier); 16 n-chunk slices
// stored plain+coalesced to d_ws; no atomics anywhere.
__global__ __launch_bounds__(256, 8) void icgp_partial_kernel(
    const float* __restrict__ xa,       // (B, 1024, 1, 3)
    const float* __restrict__ feat,     // (B, 1024, 5, 3)
    const float* __restrict__ xt,       // (B, 1024, 1, 3)
    const float* __restrict__ log_std,  // (1, 5, 3)
    float* __restrict__ pws)            // (16, B*1024*15) partials
{
    // staging: feat 64 rows x 16 fl = [0,1024) ; xa 64 rows x 4 fl = [1024,1280)
    // epilogue overlays [0,3840) after the post-loop barrier.
    __shared__ float lds[3840];         // 15360 B -> LDS allows 10 blocks/CU

    const int bid  = blockIdx.x;
    const int nsb  = bid & 15;          // n-chunk (64 n's)
    const int mt   = (bid >> 4) & 15;   // m-tile (64 m's)
    const int b    = bid >> 8;
    const int tid  = threadIdx.x;
    const int wv   = tid >> 6;          // 0..3
    const int lane = tid & 63;
    const int m    = mt * 64 + lane;
    const int n0   = nsb * 64;

    // ---- stage feat (960 fl) and xa (192 fl) into padded rows ----
    const float* __restrict__ fg = feat + ((size_t)b * 1024 + n0) * 15; // 16B-aligned
    if (tid < 240) {
        const f4a v = *(const f4a*)(fg + tid * 4);
        #pragma unroll
        for (int e = 0; e < 4; ++e) {
            const int g = tid * 4 + e;
            const int r = g / 15, c = g - r * 15;
            lds[r * 16 + c] = v[e];
        }
    }
    const float* __restrict__ ag = xa + ((size_t)b * 1024 + n0) * 3;    // 16B-aligned
    if (tid < 48) {
        const f4a v = *(const f4a*)(ag + tid * 4);
        #pragma unroll
        for (int e = 0; e < 4; ++e) {
            const int g = tid * 4 + e;
            const int r = g / 3, c = g - r * 3;
            lds[1024 + r * 4 + c] = v[e];
        }
    }

    // ---- coefficients: wt = exp2(coef*(xa-xt)^2), coef = -0.5*log2e/std^2 ----
    float coef[15];
    #pragma unroll
    for (int kc = 0; kc < 15; ++kc) {
        const float s = __expf(log_std[kc]) + EPS_F;
        coef[kc] = rfl(-0.5f * LOG2E / (s * s));
    }
    bool uni = true;
    #pragma unroll
    for (int k = 1; k < 5; ++k)
        #pragma unroll
        for (int c = 0; c < 3; ++c)
            uni = uni && (coef[k * 3 + c] == coef[c]);

    const float t0 = xt[(b * 1024 + m) * 3 + 0];
    const float t1 = xt[(b * 1024 + m) * 3 + 1];
    const float t2 = xt[(b * 1024 + m) * 3 + 2];

    __syncthreads();

    float acc[15];
    #pragma unroll
    for (int kc = 0; kc < 15; ++kc) acc[kc] = 0.0f;

    const int rb = wv * 16;             // this wave's first row

    if (uni) {
        const float c0 = coef[0], c1 = coef[1], c2 = coef[2];
        #pragma unroll 2
        for (int i = 0; i < 16; ++i) {
            const float* __restrict__ row = &lds[(rb + i) * 16];
            const f4a fA = *(const f4a*)(row);        // kc 0..3
            const f4a fB = *(const f4a*)(row + 4);    // kc 4..7
            const f4a fC = *(const f4a*)(row + 8);    // kc 8..11
            const f4a fD = *(const f4a*)(row + 12);   // kc 12..14 (+pad)
            const f4a av = *(const f4a*)(&lds[1024 + (rb + i) * 4]); // xa (+pad)
            float d0 = av.x - t0; d0 *= d0;
            float d1 = av.y - t1; d1 *= d1;
            float d2 = av.z - t2; d2 *= d2;
            const float w0 = __builtin_amdgcn_exp2f(d0 * c0);
            const float w1 = __builtin_amdgcn_exp2f(d1 * c1);
            const float w2 = __builtin_amdgcn_exp2f(d2 * c2);
            acc[0]  += w0 * fA.x;  acc[1]  += w1 * fA.y;  acc[2]  += w2 * fA.z;
            acc[3]  += w0 * fA.w;  acc[4]  += w1 * fB.x;  acc[5]  += w2 * fB.y;
            acc[6]  += w0 * fB.z;  acc[7]  += w1 * fB.w;  acc[8]  += w2 * fC.x;
            acc[9]  += w0 * fC.y;  acc[10] += w1 * fC.z;  acc[11] += w2 * fC.w;
            acc[12] += w0 * fD.x;  acc[13] += w1 * fD.y;  acc[14] += w2 * fD.z;
        }
    } else {
        // General path: 15 exps per n (correct for arbitrary log_std).
        for (int i = 0; i < 16; ++i) {
            const float* __restrict__ row = &lds[(rb + i) * 16];
            float fv[16];
            *(f4a*)(fv)      = *(const f4a*)(row);
            *(f4a*)(fv + 4)  = *(const f4a*)(row + 4);
            *(f4a*)(fv + 8)  = *(const f4a*)(row + 8);
            *(f4a*)(fv + 12) = *(const f4a*)(row + 12);
            const f4a av = *(const f4a*)(&lds[1024 + (rb + i) * 4]);
            float dd[3];
            dd[0] = av.x - t0; dd[0] *= dd[0];
            dd[1] = av.y - t1; dd[1] *= dd[1];
            dd[2] = av.z - t2; dd[2] *= dd[2];
            #pragma unroll
            for (int k = 0; k < 5; ++k)
                #pragma unroll
                for (int c = 0; c < 3; ++c)
                    acc[k * 3 + c] +=
                        __builtin_amdgcn_exp2f(dd[c] * coef[k * 3 + c]) * fv[k * 3 + c];
        }
    }

    // ---- in-block combine of 4 wave-partials (overlay staging region) ----
    __syncthreads();                    // staging no longer needed
    #pragma unroll
    for (int kc = 0; kc < 15; ++kc) lds[tid * 15 + kc] = acc[kc];
    __syncthreads();

    float* __restrict__ pb = pws + (size_t)nsb * 122880
                                 + ((size_t)b * 1024 + mt * 64) * 15;
    #pragma unroll
    for (int j = 0; j < 4; ++j) {
        const int o = j * 256 + tid;            // 0..959
        if (o < 960) {
            const int mm = o / 15, kc = o - mm * 15;
            float s = 0.0f;
            #pragma unroll
            for (int w = 0; w < 4; ++w)
                s += lds[(w * 64 + mm) * 15 + kc];
            pb[o] = s;                           // coalesced
        }
    }
}

// Kernel 2: sum the 16 n-chunk slices, float4-vectorized.
// 30720 float4 outputs; grid 120 x 256, each thread: 16 f4 loads + 1 f4 store.
__global__ __launch_bounds__(256) void icgp_reduce_kernel(
    const float* __restrict__ pws, float* __restrict__ out)
{
    const int idx = blockIdx.x * 256 + threadIdx.x;   // < 30720
    f4a s = {0.0f, 0.0f, 0.0f, 0.0f};
    #pragma unroll
    for (int ns = 0; ns < 16; ++ns) {
        const f4a v = *(const f4a*)(pws + (size_t)ns * 122880 + idx * 4);
        s.x += v.x; s.y += v.y; s.z += v.z; s.w += v.w;
    }
    *(f4a*)(out + idx * 4) = s;
}

extern "C" void kernel_launch(void* const* d_in, const int* in_sizes, int n_in,
                              void* d_out, int out_size, void* d_ws, size_t ws_size,
                              hipStream_t stream) {
    const float* xa      = (const float*)d_in[0];  // (8,1024,1,3)
    const float* feat    = (const float*)d_in[1];  // (8,1024,5,3)
    const float* xt      = (const float*)d_in[2];  // (8,1024,1,3)
    const float* log_std = (const float*)d_in[3];  // (1,5,3)
    float* out = (float*)d_out;                    // (8,1024,5,3)
    float* pws = (float*)d_ws;                     // 16 x 122880 floats = 7.9 MB

    icgp_partial_kernel<<<dim3(2048), dim3(256), 0, stream>>>(xa, feat, xt, log_std, pws);
    icgp_reduce_kernel<<<dim3(120), dim3(256), 0, stream>>>(pws, out);
}

// Round 7
// 74.290 us; speedup vs baseline: 1.0371x; 1.0371x over previous
//
#include <hip/hip_runtime.h>

#define EPS_F 1e-6f
#define LOG2E 1.4426950408889634f

typedef float f4a __attribute__((ext_vector_type(4), aligned(16)));

// Kernel 0: precompute per-(k,c) coefficients once (removes 15 exp + 15 fdiv
// from every block of the main kernel). cb[0..14] = -0.5*log2e/std^2,
// cb[15] = 1.0 if all K coefs identical per channel (fast-path flag).
__global__ void icgp_coef_kernel(const float* __restrict__ log_std,
                                 float* __restrict__ cb) {
    if (threadIdx.x == 0) {
        float c[15];
        #pragma unroll
        for (int kc = 0; kc < 15; ++kc) {
            const float s = __expf(log_std[kc]) + EPS_F;
            c[kc] = -0.5f * LOG2E / (s * s);
        }
        bool uni = true;
        #pragma unroll
        for (int k = 1; k < 5; ++k)
            #pragma unroll
            for (int ch = 0; ch < 3; ++ch)
                uni = uni && (c[k * 3 + ch] == c[ch]);
        #pragma unroll
        for (int kc = 0; kc < 15; ++kc) cb[kc] = c[kc];
        cb[15] = uni ? 1.0f : 0.0f;
    }
}

// Kernel 1: partial sums.
// grid = 1024 = B(8) x m-tiles(16, 64 m) x n-chunks(8, 128 n); block = 4 waves.
// lane <-> m; wave wv covers n in [nc*128 + wv*32, +32). All per-n data
// (feat row, xa row) is WAVE-UNIFORM: indexed from a readfirstlane'd row base
// off const __restrict pointers -> scalar (SMEM s_load) path, zero VMEM and
// zero LDS in the inner loop. No staging, no coef setup: per-block overhead
// is one 16-float uniform load + 3 xt loads. 4-wave partials combined in LDS;
// 8 n-chunk slices stored plain+coalesced to d_ws; no atomics.
__global__ __launch_bounds__(256, 4) void icgp_partial_kernel(
    const float* __restrict__ xa,       // (B, 1024, 1, 3)
    const float* __restrict__ feat,     // (B, 1024, 5, 3)
    const float* __restrict__ xt,       // (B, 1024, 1, 3)
    const float* __restrict__ cb,       // 15 coefs + flag (disjoint d_ws region)
    float* __restrict__ pws)            // (8, B*1024*15) partials
{
    __shared__ float lds[3840];         // epilogue combine only (15360 B)

    const int bid  = blockIdx.x;
    const int nc   = bid & 7;           // n-chunk (128 n's)
    const int mt   = (bid >> 3) & 15;   // m-tile (64 m's)
    const int b    = bid >> 7;
    const int tid  = threadIdx.x;
    const int wv   = tid >> 6;          // 0..3
    const int lane = tid & 63;
    const int m    = mt * 64 + lane;

    // Uniform coefficient load (merged s_load, SGPR-resident).
    float coef[15];
    #pragma unroll
    for (int kc = 0; kc < 15; ++kc) coef[kc] = cb[kc];
    const bool uni = (cb[15] != 0.0f);

    // Per-lane target point (3 VGPRs).
    const float t0 = xt[(b * 1024 + m) * 3 + 0];
    const float t1 = xt[(b * 1024 + m) * 3 + 1];
    const float t2 = xt[(b * 1024 + m) * 3 + 2];

    // Wave-uniform row base (forces SGPR index -> scalar loads below).
    const int rw = __builtin_amdgcn_readfirstlane(nc * 128 + wv * 32);
    const float* __restrict__ fg = feat + (size_t)b * 1024 * 15;
    const float* __restrict__ ag = xa   + (size_t)b * 1024 * 3;

    float acc[15];
    #pragma unroll
    for (int kc = 0; kc < 15; ++kc) acc[kc] = 0.0f;

    if (uni) {
        const float c0 = coef[0], c1 = coef[1], c2 = coef[2];
        #pragma unroll 4
        for (int i = 0; i < 32; ++i) {
            const int r = rw + i;                       // uniform
            const float* __restrict__ f = fg + r * 15;  // uniform row
            const float a0 = ag[r * 3 + 0];             // uniform xa
            const float a1 = ag[r * 3 + 1];
            const float a2 = ag[r * 3 + 2];
            float d0 = a0 - t0; d0 *= d0;
            float d1 = a1 - t1; d1 *= d1;
            float d2 = a2 - t2; d2 *= d2;
            const float w0 = __builtin_amdgcn_exp2f(d0 * c0);
            const float w1 = __builtin_amdgcn_exp2f(d1 * c1);
            const float w2 = __builtin_amdgcn_exp2f(d2 * c2);
            acc[0]  += w0 * f[0];   acc[1]  += w1 * f[1];   acc[2]  += w2 * f[2];
            acc[3]  += w0 * f[3];   acc[4]  += w1 * f[4];   acc[5]  += w2 * f[5];
            acc[6]  += w0 * f[6];   acc[7]  += w1 * f[7];   acc[8]  += w2 * f[8];
            acc[9]  += w0 * f[9];   acc[10] += w1 * f[10];  acc[11] += w2 * f[11];
            acc[12] += w0 * f[12];  acc[13] += w1 * f[13];  acc[14] += w2 * f[14];
        }
    } else {
        // General path: 15 exps per n (correct for arbitrary log_std).
        for (int i = 0; i < 32; ++i) {
            const int r = rw + i;
            const float* __restrict__ f = fg + r * 15;
            const float a0 = ag[r * 3 + 0];
            const float a1 = ag[r * 3 + 1];
            const float a2 = ag[r * 3 + 2];
            float dd[3];
            dd[0] = a0 - t0; dd[0] *= dd[0];
            dd[1] = a1 - t1; dd[1] *= dd[1];
            dd[2] = a2 - t2; dd[2] *= dd[2];
            #pragma unroll
            for (int k = 0; k < 5; ++k)
                #pragma unroll
                for (int c = 0; c < 3; ++c)
                    acc[k * 3 + c] +=
                        __builtin_amdgcn_exp2f(dd[c] * coef[k * 3 + c]) * f[k * 3 + c];
        }
    }

    // ---- in-block combine of 4 wave-partials via LDS ----
    #pragma unroll
    for (int kc = 0; kc < 15; ++kc) lds[tid * 15 + kc] = acc[kc];
    __syncthreads();

    float* __restrict__ pb = pws + (size_t)nc * 122880
                                 + ((size_t)b * 1024 + mt * 64) * 15;
    #pragma unroll
    for (int j = 0; j < 4; ++j) {
        const int o = j * 256 + tid;            // 0..959
        if (o < 960) {
            const int mm = o / 15, kc = o - mm * 15;
            float s = 0.0f;
            #pragma unroll
            for (int w = 0; w < 4; ++w)
                s += lds[(w * 64 + mm) * 15 + kc];
            pb[o] = s;                           // coalesced
        }
    }
}

// Kernel 2: sum the 8 n-chunk slices, float4-vectorized.
// 30720 float4 outputs; grid 120 x 256: 8 f4 loads + 1 f4 store per thread.
__global__ __launch_bounds__(256) void icgp_reduce_kernel(
    const float* __restrict__ pws, float* __restrict__ out)
{
    const int idx = blockIdx.x * 256 + threadIdx.x;   // < 30720
    f4a s = {0.0f, 0.0f, 0.0f, 0.0f};
    #pragma unroll
    for (int ns = 0; ns < 8; ++ns) {
        const f4a v = *(const f4a*)(pws + (size_t)ns * 122880 + idx * 4);
        s.x += v.x; s.y += v.y; s.z += v.z; s.w += v.w;
    }
    *(f4a*)(out + idx * 4) = s;
}

extern "C" void kernel_launch(void* const* d_in, const int* in_sizes, int n_in,
                              void* d_out, int out_size, void* d_ws, size_t ws_size,
                              hipStream_t stream) {
    const float* xa      = (const float*)d_in[0];  // (8,1024,1,3)
    const float* feat    = (const float*)d_in[1];  // (8,1024,5,3)
    const float* xt      = (const float*)d_in[2];  // (8,1024,1,3)
    const float* log_std = (const float*)d_in[3];  // (1,5,3)
    float* out = (float*)d_out;                    // (8,1024,5,3)
    float* pws = (float*)d_ws;                     // 8 x 122880 floats partials
    float* cb  = pws + 8 * 122880;                 // +16 floats coef block

    icgp_coef_kernel<<<dim3(1), dim3(64), 0, stream>>>(log_std, cb);
    icgp_partial_kernel<<<dim3(1024), dim3(256), 0, stream>>>(xa, feat, xt, cb, pws);
    icgp_reduce_kernel<<<dim3(120), dim3(256), 0, stream>>>(pws, out);
}